// Round 6
// baseline (598.162 us; speedup 1.0000x reference)
//
#include <hip/hip_runtime.h>

typedef float f32x4 __attribute__((ext_vector_type(4)));
typedef short s16x8 __attribute__((ext_vector_type(8)));
typedef unsigned short u16x4 __attribute__((ext_vector_type(4)));
typedef unsigned short ushort_t;

__device__ __forceinline__ unsigned short f2bf(float f) {
    union { float f; unsigned int u; } v; v.f = f;
    unsigned int r = (v.u + 0x7fffu + ((v.u >> 16) & 1u)) >> 16;
    return (unsigned short)r;
}
__device__ __forceinline__ float bf2f(unsigned short b) {
    union { unsigned int u; float f; } v; v.u = ((unsigned int)b) << 16;
    return v.f;
}

__device__ __forceinline__ f32x4 mfma_bf16(s16x8 a, s16x8 b, f32x4 c) {
    return __builtin_amdgcn_mfma_f32_16x16x32_bf16(a, b, c, 0, 0, 0);
}

__device__ __forceinline__ void gl_lds16(const void* g, void* l) {
    __builtin_amdgcn_global_load_lds(
        (const __attribute__((address_space(1))) unsigned int*)g,
        (__attribute__((address_space(3))) unsigned int*)l, 16, 0, 0);
}

// log2(e)/sqrt(512): fold exp->exp2 conversion into Q scale
#define QSCALE 0.06375871469f
// Fixed softmax offset (log2 domain) -- exact (shift invariance); relu'd q,k
// keep scores in [0, ~16] so p = exp2(s - 18) never overflows/underflows to
// harmful degree and denominator >= 4096*2^-18 > 0.
#define FIXED_M 18.0f

// ---------------------------------------------------------------------------
// Kernel 1: QKV projection. y = relu(x @ W^T + b); q *= log2(e)/sqrt(512).
// q,k row-major [batch*4096][512]; v TRANSPOSED [batch][512][4096].
// ---------------------------------------------------------------------------
#define PLDK 40

__global__ __launch_bounds__(256) void qkv_proj(
    const float* __restrict__ x,
    const float* __restrict__ Wq, const float* __restrict__ bq,
    const float* __restrict__ Wk, const float* __restrict__ bk,
    const float* __restrict__ Wv, const float* __restrict__ bv,
    ushort_t* __restrict__ qkv_ws)
{
    const int mblk  = blockIdx.x;
    const int nblk  = blockIdx.y;
    const int which = blockIdx.z;

    const float* W    = (which == 0) ? Wq : (which == 1) ? Wk : Wv;
    const float* bias = (which == 0) ? bq : (which == 1) ? bk : bv;
    ushort_t* out = qkv_ws + (size_t)which * (8192u * 512u);
    const float scale = (which == 0) ? QSCALE : 1.0f;

    __shared__ ushort_t a_lds[128][PLDK];
    __shared__ ushort_t b_lds[128][PLDK];

    const int tid  = threadIdx.x;
    const int lane = tid & 63;
    const int wave = tid >> 6;
    const int wr = wave >> 1, wc = wave & 1;

    const int srow = tid >> 1;
    const int scol = (tid & 1) * 16;

    f32x4 acc[4][4] = {};

    for (int k0 = 0; k0 < 512; k0 += 32) {
        {
            const float* src = x + (size_t)(mblk * 128 + srow) * 512 + k0 + scol;
            ushort_t tmp[16];
            #pragma unroll
            for (int i = 0; i < 16; i++) tmp[i] = f2bf(src[i]);
            #pragma unroll
            for (int i = 0; i < 16; i++) a_lds[srow][scol + i] = tmp[i];
        }
        {
            const float* src = W + (size_t)(nblk * 128 + srow) * 512 + k0 + scol;
            ushort_t tmp[16];
            #pragma unroll
            for (int i = 0; i < 16; i++) tmp[i] = f2bf(src[i]);
            #pragma unroll
            for (int i = 0; i < 16; i++) b_lds[srow][scol + i] = tmp[i];
        }
        __syncthreads();

        s16x8 af[4], bf[4];
        #pragma unroll
        for (int m = 0; m < 4; m++)
            af[m] = *reinterpret_cast<const s16x8*>(&a_lds[wr * 64 + m * 16 + (lane & 15)][(lane >> 4) * 8]);
        #pragma unroll
        for (int n = 0; n < 4; n++)
            bf[n] = *reinterpret_cast<const s16x8*>(&b_lds[wc * 64 + n * 16 + (lane & 15)][(lane >> 4) * 8]);

        #pragma unroll
        for (int m = 0; m < 4; m++)
            #pragma unroll
            for (int n = 0; n < 4; n++)
                acc[m][n] = mfma_bf16(af[m], bf[n], acc[m][n]);

        __syncthreads();
    }

    if (which == 2) {
        #pragma unroll
        for (int n = 0; n < 4; n++) {
            const int col = nblk * 128 + wc * 64 + n * 16 + (lane & 15);
            const float b = bias[col];
            #pragma unroll
            for (int m = 0; m < 4; m++) {
                const int rowb = mblk * 128 + wr * 64 + m * 16 + (lane >> 4) * 4;
                const int batch = rowb >> 12, sr = rowb & 4095;
                u16x4 pk;
                #pragma unroll
                for (int j = 0; j < 4; j++)
                    pk[j] = f2bf(fmaxf(acc[m][n][j] + b, 0.0f));
                *reinterpret_cast<u16x4*>(out + (size_t)batch * 512 * 4096 +
                                          (size_t)col * 4096 + sr) = pk;
            }
        }
    } else {
        #pragma unroll
        for (int n = 0; n < 4; n++) {
            const int col = nblk * 128 + wc * 64 + n * 16 + (lane & 15);
            const float b = bias[col];
            #pragma unroll
            for (int m = 0; m < 4; m++) {
                #pragma unroll
                for (int j = 0; j < 4; j++) {
                    const int row = mblk * 128 + wr * 64 + m * 16 + (lane >> 4) * 4 + j;
                    float v = fmaxf(acc[m][n][j] + b, 0.0f) * scale;
                    out[(size_t)row * 512 + col] = f2bf(v);
                }
            }
        }
    }
}

// ---------------------------------------------------------------------------
// Kernel 2: flash attention, cross-tile pipelined: QK(t+1) interleaved with
// PV(t) in one dependency-free MFMA block; counted vmcnt(8) keeps V(t+1)'s
// stage in flight across barriers. 4 waves x 32 q-rows, fixed-offset softmax.
// grid = (2*SP, 32).
// ---------------------------------------------------------------------------
__global__ __launch_bounds__(256, 1) void attn_v6(
    const ushort_t* __restrict__ qkv_ws,
    ushort_t* __restrict__ opart, float* __restrict__ ml,
    float* __restrict__ out, int SP, int NK)
{
    const int combo = blockIdx.x;
    const int batch = combo / SP;
    const int split = combo % SP;
    const int qblk  = blockIdx.y;
    const int tid = threadIdx.x, lane = tid & 63, wave = tid >> 6;
    const int kv00 = split * (4096 / SP);

    const ushort_t* q_ws  = qkv_ws;
    const ushort_t* k_ws  = qkv_ws + (size_t)8192 * 512;
    const ushort_t* vt_ws = qkv_ws + (size_t)2 * 8192 * 512;  // [batch][512][4096]
    const size_t base  = (size_t)batch * 4096 * 512;
    const size_t vbase = (size_t)batch * 512 * 4096;

    __shared__ ushort_t k_lds[2][32 * 512];    // 2 x 32KB, swizzled
    __shared__ ushort_t vt_lds[2][512 * 32];   // 2 x 32KB, swizzled
    __shared__ ushort_t p_lds[4][32][40];      // per-wave P bounce (32 rows)

    const int g = lane >> 4;

    // resident Q fragments: 2 row-frags x 16 k-steps (128 VGPR)
    s16x8 qf0[16], qf1[16];
    {
        const int qrow0 = qblk * 128 + wave * 32 + (lane & 15);
        const ushort_t* qp0 = q_ws + base + (size_t)qrow0 * 512 + g * 8;
        const ushort_t* qp1 = qp0 + 16 * 512;
        #pragma unroll
        for (int ks = 0; ks < 16; ks++) {
            qf0[ks] = *reinterpret_cast<const s16x8*>(qp0 + ks * 32);
            qf1[ks] = *reinterpret_cast<const s16x8*>(qp1 + ks * 32);
        }
    }

    const f32x4 zf = {0.f, 0.f, 0.f, 0.f};
    f32x4 o0[32], o1[32];
    #pragma unroll
    for (int n = 0; n < 32; n++) { o0[n] = zf; o1[n] = zf; }
    float lrow[2][4];
    #pragma unroll
    for (int f = 0; f < 2; f++)
        #pragma unroll
        for (int j = 0; j < 4; j++) lrow[f][j] = 0.0f;

    // 8 K-loads then 8 V-loads per STAGE pair (order matters for vmcnt ledger)
#define STAGE_K(BUF, KV0)                                                       \
    do {                                                                        \
        _Pragma("unroll")                                                       \
        for (int i = 0; i < 8; i++) {                                           \
            const int C   = i * 4096 + tid * 16;                                \
            const int row = C >> 10;                                            \
            const int Lc  = (C & 1023) ^ ((row & 7) << 4);                      \
            gl_lds16(k_ws + base + (size_t)((KV0) + row) * 512 + (Lc >> 1),     \
                     (char*)&k_lds[BUF][0] + C);                                \
        }                                                                       \
    } while (0)
#define STAGE_V(BUF, KV0)                                                       \
    do {                                                                        \
        _Pragma("unroll")                                                       \
        for (int i = 0; i < 8; i++) {                                           \
            const int C    = i * 4096 + tid * 16;                               \
            const int drow = C >> 6;                                            \
            const int gc   = (C >> 4) & 3;                                      \
            const int gl   = gc ^ ((drow >> 1) & 3);                            \
            gl_lds16(vt_ws + vbase + (size_t)drow * 4096 + (KV0) + gl * 8,      \
                     (char*)&vt_lds[BUF][0] + C);                               \
        }                                                                       \
    } while (0)

    f32x4 s00, s01, s10, s11;

    // ---- prologue: stage tile0, wait K0 (V0 stays in flight), QK(0)
    STAGE_K(0, kv00);
    STAGE_V(0, kv00);
    asm volatile("s_waitcnt vmcnt(8)" ::: "memory");   // K0 landed
    __builtin_amdgcn_s_barrier();

    s00 = zf; s01 = zf; s10 = zf; s11 = zf;
    {
        const char* kb = (const char*)&k_lds[0][0];
        #pragma unroll
        for (int ks = 0; ks < 16; ++ks) {
            const int key0 = lane & 15;
            const s16x8 kf0 = *reinterpret_cast<const s16x8*>(
                kb + key0 * 1024 + ((ks * 64 + g * 16) ^ ((key0 & 7) << 4)));
            s00 = mfma_bf16(qf0[ks], kf0, s00);
            s10 = mfma_bf16(qf1[ks], kf0, s10);
            const int key1 = 16 + (lane & 15);
            const s16x8 kf1 = *reinterpret_cast<const s16x8*>(
                kb + key1 * 1024 + ((ks * 64 + g * 16) ^ ((key1 & 7) << 4)));
            s01 = mfma_bf16(qf0[ks], kf1, s01);
            s11 = mfma_bf16(qf1[ks], kf1, s11);
        }
    }
    if (NK > 1) { STAGE_K(1, kv00 + 32); STAGE_V(1, kv00 + 32); }
    // outstanding now: V0(8) [+ K1(8) + V1(8) if NK>1]

    for (int t = 0; t < NK; ++t) {
        // ---- exp(t): P = exp2(S - FIXED_M), per-lane l partials, LDS bounce
        #pragma unroll
        for (int j = 0; j < 4; j++) {
            const float p00 = exp2f(s00[j] - FIXED_M);
            const float p01 = exp2f(s01[j] - FIXED_M);
            const float p10 = exp2f(s10[j] - FIXED_M);
            const float p11 = exp2f(s11[j] - FIXED_M);
            lrow[0][j] += p00 + p01;
            lrow[1][j] += p10 + p11;
            const int pr = g * 4 + j;
            p_lds[wave][pr][lane & 15]             = f2bf(p00);
            p_lds[wave][pr][16 + (lane & 15)]      = f2bf(p01);
            p_lds[wave][16 + pr][lane & 15]        = f2bf(p10);
            p_lds[wave][16 + pr][16 + (lane & 15)] = f2bf(p11);
        }
        const s16x8 pf0 = *reinterpret_cast<const s16x8*>(
            &p_lds[wave][lane & 15][g * 8]);
        const s16x8 pf1 = *reinterpret_cast<const s16x8*>(
            &p_lds[wave][16 + (lane & 15)][g * 8]);

        // ---- drain: {V(t), K(t+1)} must be in LDS; V(t+1) stays in flight
        if (t + 1 < NK) asm volatile("s_waitcnt vmcnt(8)" ::: "memory");
        else            asm volatile("s_waitcnt vmcnt(0)" ::: "memory");
        __builtin_amdgcn_s_barrier();

        const char* vb = (const char*)&vt_lds[t & 1][0];
        if (t + 1 < NK) {
            // ---- fused MFMA block: PV(t) || QK(t+1), zero dependencies
            const char* kb = (const char*)&k_lds[(t + 1) & 1][0];
            f32x4 ns00 = zf, ns01 = zf, ns10 = zf, ns11 = zf;
            #pragma unroll
            for (int u = 0; u < 16; ++u) {
                {
                    const int d = (2 * u) * 16 + (lane & 15);
                    const s16x8 vf = *reinterpret_cast<const s16x8*>(
                        vb + d * 64 + ((g * 16) ^ (((d >> 1) & 3) << 4)));
                    o0[2 * u] = mfma_bf16(pf0, vf, o0[2 * u]);
                    o1[2 * u] = mfma_bf16(pf1, vf, o1[2 * u]);
                }
                {
                    const int key0 = lane & 15;
                    const s16x8 kf0 = *reinterpret_cast<const s16x8*>(
                        kb + key0 * 1024 + ((u * 64 + g * 16) ^ ((key0 & 7) << 4)));
                    ns00 = mfma_bf16(qf0[u], kf0, ns00);
                    ns10 = mfma_bf16(qf1[u], kf0, ns10);
                }
                {
                    const int d = (2 * u + 1) * 16 + (lane & 15);
                    const s16x8 vf = *reinterpret_cast<const s16x8*>(
                        vb + d * 64 + ((g * 16) ^ (((d >> 1) & 3) << 4)));
                    o0[2 * u + 1] = mfma_bf16(pf0, vf, o0[2 * u + 1]);
                    o1[2 * u + 1] = mfma_bf16(pf1, vf, o1[2 * u + 1]);
                }
                {
                    const int key1 = 16 + (lane & 15);
                    const s16x8 kf1 = *reinterpret_cast<const s16x8*>(
                        kb + key1 * 1024 + ((u * 64 + g * 16) ^ ((key1 & 7) << 4)));
                    ns01 = mfma_bf16(qf0[u], kf1, ns01);
                    ns11 = mfma_bf16(qf1[u], kf1, ns11);
                }
            }
            s00 = ns00; s01 = ns01; s10 = ns10; s11 = ns11;
        } else {
            // ---- last tile: PV only
            #pragma unroll
            for (int n = 0; n < 32; ++n) {
                const int d = n * 16 + (lane & 15);
                const s16x8 vf = *reinterpret_cast<const s16x8*>(
                    vb + d * 64 + ((g * 16) ^ (((d >> 1) & 3) << 4)));
                o0[n] = mfma_bf16(pf0, vf, o0[n]);
                o1[n] = mfma_bf16(pf1, vf, o1[n]);
            }
        }
        __builtin_amdgcn_s_barrier();

        // ---- stage tile t+2 into the buffer just freed (all waves past PV(t))
        if (t + 2 < NK) {
            STAGE_K(t & 1, kv00 + (t + 2) * 32);
            STAGE_V(t & 1, kv00 + (t + 2) * 32);
        }
    }
#undef STAGE_K
#undef STAGE_V

    // ---- epilogue: reduce l across the 16-lane key dimension (once)
    #pragma unroll
    for (int j = 0; j < 4; j++) {
        #pragma unroll
        for (int msk = 8; msk >= 1; msk >>= 1) {
            lrow[0][j] += __shfl_xor(lrow[0][j], msk, 64);
            lrow[1][j] += __shfl_xor(lrow[1][j], msk, 64);
        }
    }

    const int qrowb = qblk * 128 + wave * 32;
    if (opart != nullptr) {
        const size_t prow8k = (size_t)batch * 4096;
        if ((lane & 15) == 0) {
            #pragma unroll
            for (int j = 0; j < 4; j++) {
                const size_t r0 = prow8k + qrowb + g * 4 + j;
                ml[((size_t)split * 8192 + r0) * 2 + 1] = lrow[0][j];
                const size_t r1 = r0 + 16;
                ml[((size_t)split * 8192 + r1) * 2 + 1] = lrow[1][j];
            }
        }
        ushort_t* op = opart + (size_t)split * 8192 * 512;
        #pragma unroll
        for (int n = 0; n < 32; n++) {
            #pragma unroll
            for (int j = 0; j < 4; j++) {
                const size_t r0 = prow8k + qrowb + g * 4 + j;
                op[r0 * 512 + n * 16 + (lane & 15)] = f2bf(o0[n][j]);
                op[(r0 + 16) * 512 + n * 16 + (lane & 15)] = f2bf(o1[n][j]);
            }
        }
    } else {
        float inv0[4], inv1[4];
        #pragma unroll
        for (int j = 0; j < 4; j++) {
            inv0[j] = 1.0f / lrow[0][j];
            inv1[j] = 1.0f / lrow[1][j];
        }
        #pragma unroll
        for (int n = 0; n < 32; n++) {
            #pragma unroll
            for (int j = 0; j < 4; j++) {
                const int row = qrowb + g * 4 + j;
                out[base + (size_t)row * 512 + n * 16 + (lane & 15)] = o0[n][j] * inv0[j];
                out[base + (size_t)(row + 16) * 512 + n * 16 + (lane & 15)] = o1[n][j] * inv1[j];
            }
        }
    }
}

// ---------------------------------------------------------------------------
// Kernel 3: merge KV-split partials. Fixed-M => equal weights:
// out = (sum_s O_s) / (sum_s l_s). 1 wave/row, 4 rows/block.
// ---------------------------------------------------------------------------
__global__ __launch_bounds__(256) void merge_kernel(
    const ushort_t* __restrict__ opart, const float* __restrict__ ml,
    float* __restrict__ out, int SP)
{
    const int row  = blockIdx.x * 4 + (threadIdx.x >> 6);
    const int lane = threadIdx.x & 63;

    float denom = 0.0f;
    for (int s = 0; s < SP; s++)
        denom += ml[((size_t)s * 8192 + row) * 2 + 1];
    const float inv = 1.0f / denom;

    float acc[8] = {};
    for (int s = 0; s < SP; s++) {
        const s16x8 v = *reinterpret_cast<const s16x8*>(
            opart + ((size_t)s * 8192 + row) * 512 + lane * 8);
        #pragma unroll
        for (int i = 0; i < 8; i++)
            acc[i] += bf2f((ushort_t)v[i]);
    }
    float* dst = out + (size_t)row * 512 + lane * 8;
    #pragma unroll
    for (int i = 0; i < 8; i++) dst[i] = acc[i] * inv;
}

extern "C" void kernel_launch(void* const* d_in, const int* in_sizes, int n_in,
                              void* d_out, int out_size, void* d_ws, size_t ws_size,
                              hipStream_t stream) {
    const float* x  = (const float*)d_in[0];
    const float* Wq = (const float*)d_in[1];
    const float* bq = (const float*)d_in[2];
    const float* Wk = (const float*)d_in[3];
    const float* bk = (const float*)d_in[4];
    const float* Wv = (const float*)d_in[5];
    const float* bv = (const float*)d_in[6];
    float* out = (float*)d_out;
    ushort_t* qkv = (ushort_t*)d_ws;  // q | k | vt, each 8192*512 bf16
    (void)in_sizes; (void)n_in; (void)out_size;

    const size_t qkv_bytes = 3ull * 8192 * 512 * 2;  // 25165824

    int SP = 0;
    if (ws_size >= qkv_bytes + 4ull * (8388608 + 65536)) SP = 4;
    else if (ws_size >= qkv_bytes + 2ull * (8388608 + 65536)) SP = 2;
    else if (ws_size >= qkv_bytes + 1ull * (8388608 + 65536)) SP = 1;

    dim3 gp(64, 4, 3);
    qkv_proj<<<gp, 256, 0, stream>>>(x, Wq, bq, Wk, bk, Wv, bv, qkv);

    if (SP > 0) {
        ushort_t* opart = qkv + 3ull * 8192 * 512;
        float* ml = (float*)(opart + (size_t)SP * 8192 * 512);
        dim3 ga(2 * SP, 32);
        attn_v6<<<ga, 256, 0, stream>>>(qkv, opart, ml, out, SP, (4096 / SP) / 32);
        merge_kernel<<<2048, 256, 0, stream>>>(opart, ml, out, SP);
    } else {
        dim3 ga(2, 32);
        attn_v6<<<ga, 256, 0, stream>>>(qkv, nullptr, nullptr, out, 1, 128);
    }
}

// Round 7
// 549.720 us; speedup vs baseline: 1.0881x; 1.0881x over previous
//
#include <hip/hip_runtime.h>

typedef float f32x4 __attribute__((ext_vector_type(4)));
typedef short s16x8 __attribute__((ext_vector_type(8)));
typedef unsigned short u16x4 __attribute__((ext_vector_type(4)));
typedef unsigned short ushort_t;

__device__ __forceinline__ unsigned short f2bf(float f) {
    union { float f; unsigned int u; } v; v.f = f;
    unsigned int r = (v.u + 0x7fffu + ((v.u >> 16) & 1u)) >> 16;
    return (unsigned short)r;
}
__device__ __forceinline__ float bf2f(unsigned short b) {
    union { unsigned int u; float f; } v; v.u = ((unsigned int)b) << 16;
    return v.f;
}

__device__ __forceinline__ f32x4 mfma_bf16(s16x8 a, s16x8 b, f32x4 c) {
    return __builtin_amdgcn_mfma_f32_16x16x32_bf16(a, b, c, 0, 0, 0);
}

__device__ __forceinline__ void gl_lds16(const void* g, void* l) {
    __builtin_amdgcn_global_load_lds(
        (const __attribute__((address_space(1))) unsigned int*)g,
        (__attribute__((address_space(3))) unsigned int*)l, 16, 0, 0);
}

// log2(e)/sqrt(512): fold exp->exp2 conversion into Q scale
#define QSCALE 0.06375871469f
// Fixed softmax offset (log2 domain) -- exact by shift-invariance; relu'd q,k
// keep scores in [0, ~16]; denominator >= 4096*2^-18 > 0.
#define FIXED_M 18.0f

// K tile LDS geometry: 32 rows x 520 ushorts (1040B row stride; 1024B data +
// 16B pad). 260 dwords % 32 banks = 4 -> 16 keys cover 8 bank-groups = 2-way
// (free). All QK reads become base + immediate offsets.
#define KROW 520
#define KROWB 1040
#define KBUFB (32 * KROWB)   // 33280 B per buffer

// ---------------------------------------------------------------------------
// Kernel 1: QKV projection. y = relu(x @ W^T + b); q *= log2(e)/sqrt(512).
// q,k row-major [batch*4096][512]; v TRANSPOSED [batch][512][4096].
// ---------------------------------------------------------------------------
#define PLDK 40

__global__ __launch_bounds__(256) void qkv_proj(
    const float* __restrict__ x,
    const float* __restrict__ Wq, const float* __restrict__ bq,
    const float* __restrict__ Wk, const float* __restrict__ bk,
    const float* __restrict__ Wv, const float* __restrict__ bv,
    ushort_t* __restrict__ qkv_ws)
{
    const int mblk  = blockIdx.x;
    const int nblk  = blockIdx.y;
    const int which = blockIdx.z;

    const float* W    = (which == 0) ? Wq : (which == 1) ? Wk : Wv;
    const float* bias = (which == 0) ? bq : (which == 1) ? bk : bv;
    ushort_t* out = qkv_ws + (size_t)which * (8192u * 512u);
    const float scale = (which == 0) ? QSCALE : 1.0f;

    __shared__ ushort_t a_lds[128][PLDK];
    __shared__ ushort_t b_lds[128][PLDK];

    const int tid  = threadIdx.x;
    const int lane = tid & 63;
    const int wave = tid >> 6;
    const int wr = wave >> 1, wc = wave & 1;

    const int srow = tid >> 1;
    const int scol = (tid & 1) * 16;

    f32x4 acc[4][4] = {};

    for (int k0 = 0; k0 < 512; k0 += 32) {
        {
            const float* src = x + (size_t)(mblk * 128 + srow) * 512 + k0 + scol;
            ushort_t tmp[16];
            #pragma unroll
            for (int i = 0; i < 16; i++) tmp[i] = f2bf(src[i]);
            #pragma unroll
            for (int i = 0; i < 16; i++) a_lds[srow][scol + i] = tmp[i];
        }
        {
            const float* src = W + (size_t)(nblk * 128 + srow) * 512 + k0 + scol;
            ushort_t tmp[16];
            #pragma unroll
            for (int i = 0; i < 16; i++) tmp[i] = f2bf(src[i]);
            #pragma unroll
            for (int i = 0; i < 16; i++) b_lds[srow][scol + i] = tmp[i];
        }
        __syncthreads();

        s16x8 af[4], bf[4];
        #pragma unroll
        for (int m = 0; m < 4; m++)
            af[m] = *reinterpret_cast<const s16x8*>(&a_lds[wr * 64 + m * 16 + (lane & 15)][(lane >> 4) * 8]);
        #pragma unroll
        for (int n = 0; n < 4; n++)
            bf[n] = *reinterpret_cast<const s16x8*>(&b_lds[wc * 64 + n * 16 + (lane & 15)][(lane >> 4) * 8]);

        #pragma unroll
        for (int m = 0; m < 4; m++)
            #pragma unroll
            for (int n = 0; n < 4; n++)
                acc[m][n] = mfma_bf16(af[m], bf[n], acc[m][n]);

        __syncthreads();
    }

    if (which == 2) {
        #pragma unroll
        for (int n = 0; n < 4; n++) {
            const int col = nblk * 128 + wc * 64 + n * 16 + (lane & 15);
            const float b = bias[col];
            #pragma unroll
            for (int m = 0; m < 4; m++) {
                const int rowb = mblk * 128 + wr * 64 + m * 16 + (lane >> 4) * 4;
                const int batch = rowb >> 12, sr = rowb & 4095;
                u16x4 pk;
                #pragma unroll
                for (int j = 0; j < 4; j++)
                    pk[j] = f2bf(fmaxf(acc[m][n][j] + b, 0.0f));
                *reinterpret_cast<u16x4*>(out + (size_t)batch * 512 * 4096 +
                                          (size_t)col * 4096 + sr) = pk;
            }
        }
    } else {
        #pragma unroll
        for (int n = 0; n < 4; n++) {
            const int col = nblk * 128 + wc * 64 + n * 16 + (lane & 15);
            const float b = bias[col];
            #pragma unroll
            for (int m = 0; m < 4; m++) {
                #pragma unroll
                for (int j = 0; j < 4; j++) {
                    const int row = mblk * 128 + wr * 64 + m * 16 + (lane >> 4) * 4 + j;
                    float v = fmaxf(acc[m][n][j] + b, 0.0f) * scale;
                    out[(size_t)row * 512 + col] = f2bf(v);
                }
            }
        }
    }
}

// ---------------------------------------------------------------------------
// Kernel 2: flash attention, cross-tile pipelined (PV(t) || QK(t+1) fused
// MFMA block), counted vmcnt, fixed-offset softmax, padded-K / base+imm LDS
// addressing to keep arch VGPRs low. 4 waves x 32 q-rows. grid = (2*SP, 32).
// ---------------------------------------------------------------------------
__global__ __launch_bounds__(256, 1) void attn_v7(
    const ushort_t* __restrict__ qkv_ws,
    ushort_t* __restrict__ opart, float* __restrict__ ml,
    float* __restrict__ out, int SP, int NK)
{
    const int combo = blockIdx.x;
    const int batch = combo / SP;
    const int split = combo % SP;
    const int qblk  = blockIdx.y;
    const int tid = threadIdx.x, lane = tid & 63, wave = tid >> 6;
    const int kv00 = split * (4096 / SP);

    const ushort_t* q_ws  = qkv_ws;
    const ushort_t* k_ws  = qkv_ws + (size_t)8192 * 512;
    const ushort_t* vt_ws = qkv_ws + (size_t)2 * 8192 * 512;  // [batch][512][4096]
    const size_t base  = (size_t)batch * 4096 * 512;
    const size_t vbase = (size_t)batch * 512 * 4096;

    __shared__ ushort_t k_lds[2][32 * KROW];   // 2 x 33280 B, padded rows
    __shared__ ushort_t vt_lds[2][512 * 32];   // 2 x 32768 B, XOR-swizzled
    __shared__ ushort_t p_lds[4][32][40];      // per-wave P bounce

    const int g = lane >> 4;
    const int l15 = lane & 15;

    // resident Q fragments: 2 row-frags x 16 k-steps (128 VGPR)
    s16x8 qf0[16], qf1[16];
    {
        const int qrow0 = qblk * 128 + wave * 32 + l15;
        const ushort_t* qp0 = q_ws + base + (size_t)qrow0 * 512 + g * 8;
        const ushort_t* qp1 = qp0 + 16 * 512;
        #pragma unroll
        for (int ks = 0; ks < 16; ks++) {
            qf0[ks] = *reinterpret_cast<const s16x8*>(qp0 + ks * 32);
            qf1[ks] = *reinterpret_cast<const s16x8*>(qp1 + ks * 32);
        }
    }

    const f32x4 zf = {0.f, 0.f, 0.f, 0.f};
    f32x4 o0[32], o1[32];
    #pragma unroll
    for (int n = 0; n < 32; n++) { o0[n] = zf; o1[n] = zf; }
    float lrow[2][4];
    #pragma unroll
    for (int f = 0; f < 2; f++)
        #pragma unroll
        for (int j = 0; j < 4; j++) lrow[f][j] = 0.0f;

    // per-lane LDS read bases (byte offsets within one buffer)
    const int kread_base = l15 * KROWB + g * 16;                       // + ks*64 imm, +16640 for key+16
    const int vread_base = l15 * 64 + ((g * 16) ^ (((l15 >> 1) & 3) << 4));  // + n*1024 imm

    // K staging: one gl_lds per padded row (1024B data per instruction)
#define STAGE_K(BUF, KV0)                                                       \
    do {                                                                        \
        _Pragma("unroll")                                                       \
        for (int i = 0; i < 8; i++) {                                           \
            const int r = i * 4 + wave;                                         \
            gl_lds16(k_ws + base + (size_t)((KV0) + r) * 512 + (tid & 63) * 8,  \
                     (char*)&k_lds[BUF][0] + r * KROWB + (tid & 63) * 16);      \
        }                                                                       \
    } while (0)
#define STAGE_V(BUF, KV0)                                                       \
    do {                                                                        \
        _Pragma("unroll")                                                       \
        for (int i = 0; i < 8; i++) {                                           \
            const int C    = i * 4096 + tid * 16;                               \
            const int drow = C >> 6;                                            \
            const int gc   = (C >> 4) & 3;                                      \
            const int gl   = gc ^ ((drow >> 1) & 3);                            \
            gl_lds16(vt_ws + vbase + (size_t)drow * 4096 + (KV0) + gl * 8,      \
                     (char*)&vt_lds[BUF][0] + C);                               \
        }                                                                       \
    } while (0)

    f32x4 s00, s01, s10, s11;

    // ---- prologue: stage tile0; wait K0 (V0 in flight); QK(0)
    STAGE_K(0, kv00);
    STAGE_V(0, kv00);
    asm volatile("s_waitcnt vmcnt(8)" ::: "memory");
    __builtin_amdgcn_s_barrier();

    s00 = zf; s01 = zf; s10 = zf; s11 = zf;
    {
        const char* kp = (const char*)&k_lds[0][0] + kread_base;
        #pragma unroll
        for (int ks = 0; ks < 16; ++ks) {
            const s16x8 kf0 = *reinterpret_cast<const s16x8*>(kp + ks * 64);
            const s16x8 kf1 = *reinterpret_cast<const s16x8*>(kp + 16640 + ks * 64);
            s00 = mfma_bf16(qf0[ks], kf0, s00);
            s10 = mfma_bf16(qf1[ks], kf0, s10);
            s01 = mfma_bf16(qf0[ks], kf1, s01);
            s11 = mfma_bf16(qf1[ks], kf1, s11);
        }
    }
    if (NK > 1) { STAGE_K(1, kv00 + 32); STAGE_V(1, kv00 + 32); }
    // outstanding: V0(8) [+ K1(8) + V1(8)]

    for (int t = 0; t < NK; ++t) {
        // ---- exp(t): consume S -> P (bf16 bounce) + per-lane l partials;
        //      then S is re-zeroed and reused as QK(t+1) accumulator.
        #pragma unroll
        for (int j = 0; j < 4; j++) {
            const float p00 = exp2f(s00[j] - FIXED_M);
            const float p01 = exp2f(s01[j] - FIXED_M);
            const float p10 = exp2f(s10[j] - FIXED_M);
            const float p11 = exp2f(s11[j] - FIXED_M);
            lrow[0][j] += p00 + p01;
            lrow[1][j] += p10 + p11;
            const int pr = g * 4 + j;
            p_lds[wave][pr][l15]            = f2bf(p00);
            p_lds[wave][pr][16 + l15]       = f2bf(p01);
            p_lds[wave][16 + pr][l15]       = f2bf(p10);
            p_lds[wave][16 + pr][16 + l15]  = f2bf(p11);
        }
        s00 = zf; s01 = zf; s10 = zf; s11 = zf;

        const s16x8 pf0 = *reinterpret_cast<const s16x8*>(&p_lds[wave][l15][g * 8]);
        const s16x8 pf1 = *reinterpret_cast<const s16x8*>(&p_lds[wave][16 + l15][g * 8]);

        // ---- drain: {V(t), K(t+1)} in LDS; V(t+1) stays in flight
        if (t + 1 < NK) asm volatile("s_waitcnt vmcnt(8)" ::: "memory");
        else            asm volatile("s_waitcnt vmcnt(0)" ::: "memory");
        __builtin_amdgcn_s_barrier();

        const char* vp = (const char*)&vt_lds[t & 1][0] + vread_base;
        if (t + 1 < NK) {
            // ---- fused MFMA block: PV(t) || QK(t+1) (accumulate into s*)
            const char* kp = (const char*)&k_lds[(t + 1) & 1][0] + kread_base;
            #pragma unroll
            for (int u = 0; u < 16; ++u) {
                {
                    const s16x8 vf = *reinterpret_cast<const s16x8*>(vp + (2 * u) * 1024);
                    o0[2 * u] = mfma_bf16(pf0, vf, o0[2 * u]);
                    o1[2 * u] = mfma_bf16(pf1, vf, o1[2 * u]);
                }
                {
                    const s16x8 kf0 = *reinterpret_cast<const s16x8*>(kp + u * 64);
                    s00 = mfma_bf16(qf0[u], kf0, s00);
                    s10 = mfma_bf16(qf1[u], kf0, s10);
                }
                {
                    const s16x8 vf = *reinterpret_cast<const s16x8*>(vp + (2 * u + 1) * 1024);
                    o0[2 * u + 1] = mfma_bf16(pf0, vf, o0[2 * u + 1]);
                    o1[2 * u + 1] = mfma_bf16(pf1, vf, o1[2 * u + 1]);
                }
                {
                    const s16x8 kf1 = *reinterpret_cast<const s16x8*>(kp + 16640 + u * 64);
                    s01 = mfma_bf16(qf0[u], kf1, s01);
                    s11 = mfma_bf16(qf1[u], kf1, s11);
                }
            }
        } else {
            // ---- last tile: PV only
            #pragma unroll
            for (int n = 0; n < 32; ++n) {
                const s16x8 vf = *reinterpret_cast<const s16x8*>(vp + n * 1024);
                o0[n] = mfma_bf16(pf0, vf, o0[n]);
                o1[n] = mfma_bf16(pf1, vf, o1[n]);
            }
        }
        __builtin_amdgcn_s_barrier();

        // ---- stage tile t+2 into the buffer just freed
        if (t + 2 < NK) {
            STAGE_K(t & 1, kv00 + (t + 2) * 32);
            STAGE_V(t & 1, kv00 + (t + 2) * 32);
        }
    }
#undef STAGE_K
#undef STAGE_V

    // ---- epilogue: reduce l across the 16-lane key dimension (once)
    #pragma unroll
    for (int j = 0; j < 4; j++) {
        #pragma unroll
        for (int msk = 8; msk >= 1; msk >>= 1) {
            lrow[0][j] += __shfl_xor(lrow[0][j], msk, 64);
            lrow[1][j] += __shfl_xor(lrow[1][j], msk, 64);
        }
    }

    const int qrowb = qblk * 128 + wave * 32;
    if (opart != nullptr) {
        const size_t prow8k = (size_t)batch * 4096;
        if (l15 == 0) {
            #pragma unroll
            for (int j = 0; j < 4; j++) {
                const size_t r0 = prow8k + qrowb + g * 4 + j;
                ml[((size_t)split * 8192 + r0) * 2 + 1] = lrow[0][j];
                const size_t r1 = r0 + 16;
                ml[((size_t)split * 8192 + r1) * 2 + 1] = lrow[1][j];
            }
        }
        ushort_t* op = opart + (size_t)split * 8192 * 512;
        #pragma unroll
        for (int n = 0; n < 32; n++) {
            #pragma unroll
            for (int j = 0; j < 4; j++) {
                const size_t r0 = prow8k + qrowb + g * 4 + j;
                op[r0 * 512 + n * 16 + l15] = f2bf(o0[n][j]);
                op[(r0 + 16) * 512 + n * 16 + l15] = f2bf(o1[n][j]);
            }
        }
    } else {
        float inv0[4], inv1[4];
        #pragma unroll
        for (int j = 0; j < 4; j++) {
            inv0[j] = 1.0f / lrow[0][j];
            inv1[j] = 1.0f / lrow[1][j];
        }
        #pragma unroll
        for (int n = 0; n < 32; n++) {
            #pragma unroll
            for (int j = 0; j < 4; j++) {
                const int row = qrowb + g * 4 + j;
                out[base + (size_t)row * 512 + n * 16 + l15] = o0[n][j] * inv0[j];
                out[base + (size_t)(row + 16) * 512 + n * 16 + l15] = o1[n][j] * inv1[j];
            }
        }
    }
}

// ---------------------------------------------------------------------------
// Kernel 3: merge KV-split partials. Fixed-M => equal weights:
// out = (sum_s O_s) / (sum_s l_s). 1 wave/row, 4 rows/block.
// ---------------------------------------------------------------------------
__global__ __launch_bounds__(256) void merge_kernel(
    const ushort_t* __restrict__ opart, const float* __restrict__ ml,
    float* __restrict__ out, int SP)
{
    const int row  = blockIdx.x * 4 + (threadIdx.x >> 6);
    const int lane = threadIdx.x & 63;

    float denom = 0.0f;
    for (int s = 0; s < SP; s++)
        denom += ml[((size_t)s * 8192 + row) * 2 + 1];
    const float inv = 1.0f / denom;

    float acc[8] = {};
    for (int s = 0; s < SP; s++) {
        const s16x8 v = *reinterpret_cast<const s16x8*>(
            opart + ((size_t)s * 8192 + row) * 512 + lane * 8);
        #pragma unroll
        for (int i = 0; i < 8; i++)
            acc[i] += bf2f((ushort_t)v[i]);
    }
    float* dst = out + (size_t)row * 512 + lane * 8;
    #pragma unroll
    for (int i = 0; i < 8; i++) dst[i] = acc[i] * inv;
}

extern "C" void kernel_launch(void* const* d_in, const int* in_sizes, int n_in,
                              void* d_out, int out_size, void* d_ws, size_t ws_size,
                              hipStream_t stream) {
    const float* x  = (const float*)d_in[0];
    const float* Wq = (const float*)d_in[1];
    const float* bq = (const float*)d_in[2];
    const float* Wk = (const float*)d_in[3];
    const float* bk = (const float*)d_in[4];
    const float* Wv = (const float*)d_in[5];
    const float* bv = (const float*)d_in[6];
    float* out = (float*)d_out;
    ushort_t* qkv = (ushort_t*)d_ws;  // q | k | vt, each 8192*512 bf16
    (void)in_sizes; (void)n_in; (void)out_size;

    const size_t qkv_bytes = 3ull * 8192 * 512 * 2;  // 25165824

    int SP = 0;
    if (ws_size >= qkv_bytes + 4ull * (8388608 + 65536)) SP = 4;
    else if (ws_size >= qkv_bytes + 2ull * (8388608 + 65536)) SP = 2;
    else if (ws_size >= qkv_bytes + 1ull * (8388608 + 65536)) SP = 1;

    dim3 gp(64, 4, 3);
    qkv_proj<<<gp, 256, 0, stream>>>(x, Wq, bq, Wk, bk, Wv, bv, qkv);

    if (SP > 0) {
        ushort_t* opart = qkv + 3ull * 8192 * 512;
        float* ml = (float*)(opart + (size_t)SP * 8192 * 512);
        dim3 ga(2 * SP, 32);
        attn_v7<<<ga, 256, 0, stream>>>(qkv, opart, ml, out, SP, (4096 / SP) / 32);
        merge_kernel<<<2048, 256, 0, stream>>>(opart, ml, out, SP);
    } else {
        dim3 ga(2, 32);
        attn_v7<<<ga, 256, 0, stream>>>(qkv, nullptr, nullptr, out, 1, 128);
    }
}

// Round 8
// 241.263 us; speedup vs baseline: 2.4793x; 2.2785x over previous
//
#include <hip/hip_runtime.h>

typedef float f32x4 __attribute__((ext_vector_type(4)));
typedef short s16x8 __attribute__((ext_vector_type(8)));
typedef unsigned short u16x4 __attribute__((ext_vector_type(4)));
typedef unsigned short ushort_t;

__device__ __forceinline__ unsigned short f2bf(float f) {
    union { float f; unsigned int u; } v; v.f = f;
    unsigned int r = (v.u + 0x7fffu + ((v.u >> 16) & 1u)) >> 16;
    return (unsigned short)r;
}
__device__ __forceinline__ unsigned short tbf(float f) {  // truncate (f >= 0)
    union { float f; unsigned int u; } v; v.f = f;
    return (unsigned short)(v.u >> 16);
}
__device__ __forceinline__ float bf2f(unsigned short b) {
    union { unsigned int u; float f; } v; v.u = ((unsigned int)b) << 16;
    return v.f;
}

__device__ __forceinline__ f32x4 mfma_bf16(s16x8 a, s16x8 b, f32x4 c) {
    return __builtin_amdgcn_mfma_f32_16x16x32_bf16(a, b, c, 0, 0, 0);
}

__device__ __forceinline__ void gl_lds16(const void* g, void* l) {
    __builtin_amdgcn_global_load_lds(
        (const __attribute__((address_space(1))) unsigned int*)g,
        (__attribute__((address_space(3))) unsigned int*)l, 16, 0, 0);
}

// log2(e)/sqrt(512): fold exp->exp2 conversion into Q scale
#define QSCALE 0.06375871469f
// Fixed softmax offset (log2 domain) -- exact by shift-invariance; relu'd q,k
// keep scores in [0, ~16]; denominator >= 4096*2^-18 > 0.
#define FIXED_M 18.0f

// K tile LDS: 64 rows x 520 ushorts (1040B stride = 1024B data + 16B pad).
// 260 dwords % 32 banks = 4 -> (l15,g) read pattern is conflict-free.
#define KROW 520
#define KROWB 1040

// ---------------------------------------------------------------------------
// Kernel 1: QKV projection. y = relu(x @ W^T + b); q *= log2(e)/sqrt(512).
// q,k row-major [batch*4096][512]; v TRANSPOSED [batch][512][4096].
// ---------------------------------------------------------------------------
#define PLDK 40

__global__ __launch_bounds__(256) void qkv_proj(
    const float* __restrict__ x,
    const float* __restrict__ Wq, const float* __restrict__ bq,
    const float* __restrict__ Wk, const float* __restrict__ bk,
    const float* __restrict__ Wv, const float* __restrict__ bv,
    ushort_t* __restrict__ qkv_ws)
{
    const int mblk  = blockIdx.x;
    const int nblk  = blockIdx.y;
    const int which = blockIdx.z;

    const float* W    = (which == 0) ? Wq : (which == 1) ? Wk : Wv;
    const float* bias = (which == 0) ? bq : (which == 1) ? bk : bv;
    ushort_t* out = qkv_ws + (size_t)which * (8192u * 512u);
    const float scale = (which == 0) ? QSCALE : 1.0f;

    __shared__ ushort_t a_lds[128][PLDK];
    __shared__ ushort_t b_lds[128][PLDK];

    const int tid  = threadIdx.x;
    const int lane = tid & 63;
    const int wave = tid >> 6;
    const int wr = wave >> 1, wc = wave & 1;

    const int srow = tid >> 1;
    const int scol = (tid & 1) * 16;

    f32x4 acc[4][4] = {};

    for (int k0 = 0; k0 < 512; k0 += 32) {
        {
            const float* src = x + (size_t)(mblk * 128 + srow) * 512 + k0 + scol;
            ushort_t tmp[16];
            #pragma unroll
            for (int i = 0; i < 16; i++) tmp[i] = f2bf(src[i]);
            #pragma unroll
            for (int i = 0; i < 16; i++) a_lds[srow][scol + i] = tmp[i];
        }
        {
            const float* src = W + (size_t)(nblk * 128 + srow) * 512 + k0 + scol;
            ushort_t tmp[16];
            #pragma unroll
            for (int i = 0; i < 16; i++) tmp[i] = f2bf(src[i]);
            #pragma unroll
            for (int i = 0; i < 16; i++) b_lds[srow][scol + i] = tmp[i];
        }
        __syncthreads();

        s16x8 af[4], bf[4];
        #pragma unroll
        for (int m = 0; m < 4; m++)
            af[m] = *reinterpret_cast<const s16x8*>(&a_lds[wr * 64 + m * 16 + (lane & 15)][(lane >> 4) * 8]);
        #pragma unroll
        for (int n = 0; n < 4; n++)
            bf[n] = *reinterpret_cast<const s16x8*>(&b_lds[wc * 64 + n * 16 + (lane & 15)][(lane >> 4) * 8]);

        #pragma unroll
        for (int m = 0; m < 4; m++)
            #pragma unroll
            for (int n = 0; n < 4; n++)
                acc[m][n] = mfma_bf16(af[m], bf[n], acc[m][n]);

        __syncthreads();
    }

    if (which == 2) {
        #pragma unroll
        for (int n = 0; n < 4; n++) {
            const int col = nblk * 128 + wc * 64 + n * 16 + (lane & 15);
            const float b = bias[col];
            #pragma unroll
            for (int m = 0; m < 4; m++) {
                const int rowb = mblk * 128 + wr * 64 + m * 16 + (lane >> 4) * 4;
                const int batch = rowb >> 12, sr = rowb & 4095;
                u16x4 pk;
                #pragma unroll
                for (int j = 0; j < 4; j++)
                    pk[j] = f2bf(fmaxf(acc[m][n][j] + b, 0.0f));
                *reinterpret_cast<u16x4*>(out + (size_t)batch * 512 * 4096 +
                                          (size_t)col * 4096 + sr) = pk;
            }
        }
    } else {
        #pragma unroll
        for (int n = 0; n < 4; n++) {
            const int col = nblk * 128 + wc * 64 + n * 16 + (lane & 15);
            const float b = bias[col];
            #pragma unroll
            for (int m = 0; m < 4; m++) {
                #pragma unroll
                for (int j = 0; j < 4; j++) {
                    const int row = mblk * 128 + wr * 64 + m * 16 + (lane >> 4) * 4 + j;
                    float v = fmaxf(acc[m][n][j] + b, 0.0f) * scale;
                    out[(size_t)row * 512 + col] = f2bf(v);
                }
            }
        }
    }
}

// ---------------------------------------------------------------------------
// Kernel 2: flash attention, 64-key tiles with phase-split staging:
// V(t) stages during QK(t); K(t+1) stages during PV(t); counted vmcnt(16)
// keeps 16 loads in flight across every barrier. Fixed-offset softmax,
// 4 waves x 32 q-rows, v5 register architecture (no PV/QK fusion).
// grid = (2*SP, 32).
// ---------------------------------------------------------------------------
__global__ __launch_bounds__(256, 1) void attn_v8(
    const ushort_t* __restrict__ qkv_ws,
    ushort_t* __restrict__ opart, float* __restrict__ ml,
    float* __restrict__ out, int SP, int NK)
{
    const int combo = blockIdx.x;
    const int batch = combo / SP;
    const int split = combo % SP;
    const int qblk  = blockIdx.y;
    const int tid = threadIdx.x, lane = tid & 63, wave = tid >> 6;
    const int kv00 = split * (4096 / SP);

    const ushort_t* q_ws  = qkv_ws;
    const ushort_t* k_ws  = qkv_ws + (size_t)8192 * 512;
    const ushort_t* vt_ws = qkv_ws + (size_t)2 * 8192 * 512;  // [batch][512][4096]
    const size_t base  = (size_t)batch * 4096 * 512;
    const size_t vbase = (size_t)batch * 512 * 4096;

    __shared__ ushort_t k_lds[64 * KROW];    // 66560 B, padded rows
    __shared__ ushort_t vt_lds[512 * 64];    // 65536 B, XOR-swizzled 128B rows
    __shared__ ushort_t p_lds[4][32][72];    // 18432 B, per-wave P bounce

    const int g = lane >> 4;
    const int l15 = lane & 15;

    // resident Q fragments: 2 row-frags x 16 k-steps (128 VGPR)
    s16x8 qf0[16], qf1[16];
    {
        const int qrow0 = qblk * 128 + wave * 32 + l15;
        const ushort_t* qp0 = q_ws + base + (size_t)qrow0 * 512 + g * 8;
        const ushort_t* qp1 = qp0 + 16 * 512;
        #pragma unroll
        for (int ks = 0; ks < 16; ks++) {
            qf0[ks] = *reinterpret_cast<const s16x8*>(qp0 + ks * 32);
            qf1[ks] = *reinterpret_cast<const s16x8*>(qp1 + ks * 32);
        }
    }

    const f32x4 zf = {0.f, 0.f, 0.f, 0.f};
    f32x4 o0[32], o1[32];
    #pragma unroll
    for (int n = 0; n < 32; n++) { o0[n] = zf; o1[n] = zf; }
    float lrow[2][4];
    #pragma unroll
    for (int f = 0; f < 2; f++)
        #pragma unroll
        for (int j = 0; j < 4; j++) lrow[f][j] = 0.0f;

    // per-lane LDS read bases
    const int kread_base = l15 * KROWB + g * 16;  // + c*16640 + ks*64 imm
    const int vread0 = l15 * 128 + ((g * 16) ^ ((l15 & 7) << 4));        // keys 0-31
    const int vread1 = l15 * 128 + (((64) + g * 16) ^ ((l15 & 7) << 4)); // keys 32-63

    // K: 64 rows x 1024B data; one gl_lds16 per (row, lane) chunk.
#define STAGE_K(KV0)                                                            \
    do {                                                                        \
        _Pragma("unroll")                                                       \
        for (int i = 0; i < 16; i++) {                                          \
            const int r = i * 4 + wave;                                         \
            gl_lds16(k_ws + base + (size_t)((KV0) + r) * 512 + lane * 8,        \
                     (char*)k_lds + r * KROWB + lane * 16);                     \
        }                                                                       \
    } while (0)
    // V: 64KB tile, linear dest, inverse-swizzled source (byte ^= (d&7)<<4).
#define STAGE_V(KV0)                                                            \
    do {                                                                        \
        _Pragma("unroll")                                                       \
        for (int i = 0; i < 16; i++) {                                          \
            const int C    = i * 4096 + tid * 16;                               \
            const int drow = C >> 7;                                            \
            const int c    = C & 127;                                           \
            const int cs   = c ^ ((drow & 7) << 4);                             \
            gl_lds16(vt_ws + vbase + (size_t)drow * 4096 + (KV0) + (cs >> 1),   \
                     (char*)vt_lds + C);                                        \
        }                                                                       \
    } while (0)

    // ---- prologue: stage K0 (awaited) + V0 (in flight)
    STAGE_K(kv00);
    STAGE_V(kv00);
    asm volatile("s_waitcnt vmcnt(16)" ::: "memory");   // K0 landed
    __builtin_amdgcn_s_barrier();

    for (int t = 0; t < NK; ++t) {
        const int kv0 = kv00 + t * 64;

        // ---- QK^T : S[32 rows][64 keys], 64 ds_read + 128 MFMA
        f32x4 s0[4], s1[4];
        #pragma unroll
        for (int c = 0; c < 4; c++) { s0[c] = zf; s1[c] = zf; }
        {
            const char* kp = (const char*)k_lds + kread_base;
            #pragma unroll
            for (int ks = 0; ks < 16; ++ks) {
                #pragma unroll
                for (int c = 0; c < 4; c++) {
                    const s16x8 kf = *reinterpret_cast<const s16x8*>(
                        kp + c * 16640 + ks * 64);
                    s0[c] = mfma_bf16(qf0[ks], kf, s0[c]);
                    s1[c] = mfma_bf16(qf1[ks], kf, s1[c]);
                }
            }
        }

        // ---- exp: P = exp2(S - FIXED_M), per-lane l partials, bounce to LDS
        #pragma unroll
        for (int j = 0; j < 4; j++) {
            #pragma unroll
            for (int c = 0; c < 4; c++) {
                const float e0 = exp2f(s0[c][j] - FIXED_M);
                const float e1 = exp2f(s1[c][j] - FIXED_M);
                lrow[0][j] += e0;
                lrow[1][j] += e1;
                p_lds[wave][g * 4 + j][c * 16 + l15]      = tbf(e0);
                p_lds[wave][16 + g * 4 + j][c * 16 + l15] = tbf(e1);
            }
        }

        __builtin_amdgcn_s_barrier();              // all waves done reading K-buf

        if (t + 1 < NK) STAGE_K(kv0 + 64);         // overwrite K-buf for t+1

        // V(t) must be in LDS; K(t+1)'s 16 loads stay in flight
        if (t + 1 < NK) asm volatile("s_waitcnt vmcnt(16)" ::: "memory");
        else            asm volatile("s_waitcnt vmcnt(0)" ::: "memory");
        __builtin_amdgcn_s_barrier();

        // ---- PV: O[32][512] += P[32][64] @ V[64][512], 64 ds_read + 128 MFMA
        {
            s16x8 pf[2][2];
            #pragma unroll
            for (int f = 0; f < 2; f++)
                #pragma unroll
                for (int h = 0; h < 2; h++)
                    pf[f][h] = *reinterpret_cast<const s16x8*>(
                        &p_lds[wave][16 * f + l15][32 * h + g * 8]);

            const char* vb = (const char*)vt_lds;
            #pragma unroll
            for (int n = 0; n < 32; ++n) {
                const s16x8 vf0 = *reinterpret_cast<const s16x8*>(vb + vread0 + n * 2048);
                o0[n] = mfma_bf16(pf[0][0], vf0, o0[n]);
                o1[n] = mfma_bf16(pf[1][0], vf0, o1[n]);
                const s16x8 vf1 = *reinterpret_cast<const s16x8*>(vb + vread1 + n * 2048);
                o0[n] = mfma_bf16(pf[0][1], vf1, o0[n]);
                o1[n] = mfma_bf16(pf[1][1], vf1, o1[n]);
            }
        }

        __builtin_amdgcn_s_barrier();              // all waves done reading V-buf

        if (t + 1 < NK) {
            STAGE_V(kv0 + 64);                     // overwrite V-buf for t+1
            // K(t+1) must be in LDS before next QK; V(t+1) stays in flight
            asm volatile("s_waitcnt vmcnt(16)" ::: "memory");
            __builtin_amdgcn_s_barrier();
        }
    }
#undef STAGE_K
#undef STAGE_V

    // ---- epilogue: reduce l across the 16-lane key dimension (once)
    #pragma unroll
    for (int j = 0; j < 4; j++) {
        #pragma unroll
        for (int msk = 8; msk >= 1; msk >>= 1) {
            lrow[0][j] += __shfl_xor(lrow[0][j], msk, 64);
            lrow[1][j] += __shfl_xor(lrow[1][j], msk, 64);
        }
    }

    const int qrowb = qblk * 128 + wave * 32;
    if (opart != nullptr) {
        const size_t prow8k = (size_t)batch * 4096;
        if (l15 == 0) {
            #pragma unroll
            for (int j = 0; j < 4; j++) {
                const size_t r0 = prow8k + qrowb + g * 4 + j;
                ml[((size_t)split * 8192 + r0) * 2 + 1] = lrow[0][j];
                const size_t r1 = r0 + 16;
                ml[((size_t)split * 8192 + r1) * 2 + 1] = lrow[1][j];
            }
        }
        ushort_t* op = opart + (size_t)split * 8192 * 512;
        #pragma unroll
        for (int n = 0; n < 32; n++) {
            #pragma unroll
            for (int j = 0; j < 4; j++) {
                const size_t r0 = prow8k + qrowb + g * 4 + j;
                op[r0 * 512 + n * 16 + l15] = f2bf(o0[n][j]);
                op[(r0 + 16) * 512 + n * 16 + l15] = f2bf(o1[n][j]);
            }
        }
    } else {
        float inv0[4], inv1[4];
        #pragma unroll
        for (int j = 0; j < 4; j++) {
            inv0[j] = 1.0f / lrow[0][j];
            inv1[j] = 1.0f / lrow[1][j];
        }
        #pragma unroll
        for (int n = 0; n < 32; n++) {
            #pragma unroll
            for (int j = 0; j < 4; j++) {
                const int row = qrowb + g * 4 + j;
                out[base + (size_t)row * 512 + n * 16 + l15] = o0[n][j] * inv0[j];
                out[base + (size_t)(row + 16) * 512 + n * 16 + l15] = o1[n][j] * inv1[j];
            }
        }
    }
}

// ---------------------------------------------------------------------------
// Kernel 3: merge KV-split partials. Fixed-M => equal weights:
// out = (sum_s O_s) / (sum_s l_s). 1 wave/row, 4 rows/block.
// ---------------------------------------------------------------------------
__global__ __launch_bounds__(256) void merge_kernel(
    const ushort_t* __restrict__ opart, const float* __restrict__ ml,
    float* __restrict__ out, int SP)
{
    const int row  = blockIdx.x * 4 + (threadIdx.x >> 6);
    const int lane = threadIdx.x & 63;

    float denom = 0.0f;
    for (int s = 0; s < SP; s++)
        denom += ml[((size_t)s * 8192 + row) * 2 + 1];
    const float inv = 1.0f / denom;

    float acc[8] = {};
    for (int s = 0; s < SP; s++) {
        const s16x8 v = *reinterpret_cast<const s16x8*>(
            opart + ((size_t)s * 8192 + row) * 512 + lane * 8);
        #pragma unroll
        for (int i = 0; i < 8; i++)
            acc[i] += bf2f((ushort_t)v[i]);
    }
    float* dst = out + (size_t)row * 512 + lane * 8;
    #pragma unroll
    for (int i = 0; i < 8; i++) dst[i] = acc[i] * inv;
}

extern "C" void kernel_launch(void* const* d_in, const int* in_sizes, int n_in,
                              void* d_out, int out_size, void* d_ws, size_t ws_size,
                              hipStream_t stream) {
    const float* x  = (const float*)d_in[0];
    const float* Wq = (const float*)d_in[1];
    const float* bq = (const float*)d_in[2];
    const float* Wk = (const float*)d_in[3];
    const float* bk = (const float*)d_in[4];
    const float* Wv = (const float*)d_in[5];
    const float* bv = (const float*)d_in[6];
    float* out = (float*)d_out;
    ushort_t* qkv = (ushort_t*)d_ws;  // q | k | vt, each 8192*512 bf16
    (void)in_sizes; (void)n_in; (void)out_size;

    const size_t qkv_bytes = 3ull * 8192 * 512 * 2;  // 25165824

    int SP = 0;
    if (ws_size >= qkv_bytes + 4ull * (8388608 + 65536)) SP = 4;
    else if (ws_size >= qkv_bytes + 2ull * (8388608 + 65536)) SP = 2;
    else if (ws_size >= qkv_bytes + 1ull * (8388608 + 65536)) SP = 1;

    dim3 gp(64, 4, 3);
    qkv_proj<<<gp, 256, 0, stream>>>(x, Wq, bq, Wk, bk, Wv, bv, qkv);

    if (SP > 0) {
        ushort_t* opart = qkv + 3ull * 8192 * 512;
        float* ml = (float*)(opart + (size_t)SP * 8192 * 512);
        dim3 ga(2 * SP, 32);
        attn_v8<<<ga, 256, 0, stream>>>(qkv, opart, ml, out, SP, (4096 / SP) / 64);
        merge_kernel<<<2048, 256, 0, stream>>>(opart, ml, out, SP);
    } else {
        dim3 ga(2, 32);
        attn_v8<<<ga, 256, 0, stream>>>(qkv, nullptr, nullptr, out, 1, 64);
    }
}